// Round 16
// baseline (236.181 us; speedup 1.0000x reference)
//
#include <hip/hip_runtime.h>

#define BS 16
#define CI 2048
#define NI 16
#define CO 64
#define NO 32
#define KK 2048     // CO*NO
#define NGRP 256    // votes i-groups (frozen)
#define NGRP_R 128  // route i-groups: 16 capsules/block -> half the partials

__device__ __forceinline__ void load_lds16(const float* g, float* l) {
    __builtin_amdgcn_global_load_lds(
        (const __attribute__((address_space(1))) void*)g,
        (__attribute__((address_space(3))) void*)l, 16, 0, 0);
}

#define WAITVM12 asm volatile("s_waitcnt vmcnt(12)" ::: "memory")
#define WAITVM4  asm volatile("s_waitcnt vmcnt(4)" ::: "memory")
#define WAITVM0  asm volatile("s_waitcnt vmcnt(0)" ::: "memory")
#define WAITLGKM asm volatile("s_waitcnt lgkmcnt(0)" ::: "memory")
#define BAR __builtin_amdgcn_s_barrier
#define MEMFENCE asm volatile("" ::: "memory")

__device__ __forceinline__ unsigned bf16rne(float f) {
    unsigned u = __float_as_uint(f);
    return (u + 0x7fffu + ((u >> 16) & 1u)) >> 16;
}
__device__ __forceinline__ unsigned pack2(float lo, float hi) {
    return bf16rne(lo) | (bf16rne(hi) << 16);
}
__device__ __forceinline__ float bflo(unsigned u) { return __uint_as_float(u << 16); }
__device__ __forceinline__ float bfhi(unsigned u) { return __uint_as_float(u & 0xffff0000u); }

// ---------------- pass 0: weights -> votes(bf16) + uniform-route sums ------
// FROZEN (r12/r13/r15-proven): 512 thr, lb(512,2) -> 128 VGPR (the only
// allocator point that doesn't spill; min-wave hints trigger spill - r5/r6/r14),
// 512 blocks (sibling pairs share weights via same-XCD L2), self-sliced
// global_load_lds staging, counted vmcnt ledger incl. the 8 vote stores.
__global__ __launch_bounds__(512, 2) void votes_kernel(
    const float* __restrict__ x,      // [BS][CI][NI]
    const float* __restrict__ w,      // [CI][NI][KK]
    unsigned* __restrict__ votes,     // [CI][BS][KK/2] u32 = 2 bf16
    float* __restrict__ partials)     // [NGRP][BS][KK]
{
    __shared__ float wbuf[2][4 * KK]; // 64 KB: double-buffered 4-row quarters
    __shared__ float xb[8][8][NI];    // 4 KB

    const int t = threadIdx.x;
    const int phys = blockIdx.x;
    const int xcd = phys & 7;
    const int slot = phys >> 3;
    const int pairid = xcd * 32 + (slot >> 1);
    const int half = slot & 1;
    const int k4 = 4 * t;

    {
        int il = t >> 6, b = (t >> 3) & 7, n0 = (t & 7) * 2;
        int i = pairid + il * NGRP;
        *(float2*)&xb[il][b][n0] =
            *(const float2*)&x[((size_t)(half * 8 + b) * CI + i) * NI + n0];
    }
    __syncthreads();  // x visible; counters drained: exact ledger starts

    float4 acc[8];
#pragma unroll
    for (int b = 0; b < 8; ++b) acc[b] = make_float4(0.f, 0.f, 0.f, 0.f);

    auto issue = [&](int s) {   // quarter s: capsule s>>2, ni rows 4(s&3)..+3
        int ilp = s >> 2, qp = s & 3;
        const float* gb = w + ((size_t)(pairid + ilp * NGRP) * NI + qp * 4) * KK + k4;
        float* lb = wbuf[s & 1] + k4;
#pragma unroll
        for (int r = 0; r < 4; ++r)
            load_lds16(gb + (size_t)r * KK, lb + r * KK);
    };

    auto computequarter = [&](int il, int q, float4(&dst)[8]) {
#pragma unroll
        for (int rg = 0; rg < 2; ++rg) {
            float4 wA = *(const float4*)&wbuf[q & 1][(2 * rg) * KK + k4];
            float4 wB = *(const float4*)&wbuf[q & 1][(2 * rg + 1) * KK + k4];
#pragma unroll
            for (int b = 0; b < 8; ++b) {
                float2 xv = *(const float2*)&xb[il][b][q * 4 + 2 * rg];
                dst[b].x = fmaf(xv.x, wA.x, dst[b].x);
                dst[b].y = fmaf(xv.x, wA.y, dst[b].y);
                dst[b].z = fmaf(xv.x, wA.z, dst[b].z);
                dst[b].w = fmaf(xv.x, wA.w, dst[b].w);
                dst[b].x = fmaf(xv.y, wB.x, dst[b].x);
                dst[b].y = fmaf(xv.y, wB.y, dst[b].y);
                dst[b].z = fmaf(xv.y, wB.z, dst[b].z);
                dst[b].w = fmaf(xv.y, wB.w, dst[b].w);
            }
        }
    };

    issue(0); issue(1);

#pragma unroll 1
    for (int il = 0; il < 8; ++il) {
        float4 v[8];
#pragma unroll
        for (int b = 0; b < 8; ++b) v[b] = make_float4(0.f, 0.f, 0.f, 0.f);

#pragma unroll
        for (int q = 0; q < 4; ++q) {
            if (q < 2) { if (il > 0) { WAITVM12; } else { WAITVM4; } }
            else if (q == 3) { if (il == 7) { WAITVM0; } else { WAITVM4; } }
            else { WAITVM4; }
            computequarter(il, q, v);
            WAITLGKM;
            if (il < 7 || q < 2) issue(il * 4 + q + 2);
        }

        const size_t vbase = ((size_t)(pairid + il * NGRP) * BS + half * 8) * (KK / 2) + 2 * t;
#pragma unroll
        for (int b = 0; b < 8; ++b) {
            acc[b].x += v[b].x; acc[b].y += v[b].y;
            acc[b].z += v[b].z; acc[b].w += v[b].w;
            uint2 pk;
            pk.x = pack2(v[b].x, v[b].y);
            pk.y = pack2(v[b].z, v[b].w);
            *(uint2*)&votes[vbase + (size_t)b * (KK / 2)] = pk;
        }
        MEMFENCE;
    }

#pragma unroll
    for (int b = 0; b < 8; ++b)
        *(float4*)&partials[((size_t)pairid * BS + half * 8 + b) * KK + k4] = acc[b];
}

// ---------------- routing from bf16 votes (16 il/block, no logits) ---------
// r13/r15-proven body; now 16 capsules per block (NGRP_R=128, grid 512 =
// 2 blocks/CU unchanged) -> partials halves to 16.8 MB. Linearity: iter-3
// logits = v.(act1+act2), so route2 = route1 with summed act. ABS is the
// compile-time absolute il (0..15); vA/vB parity = ABS&1 holds across the
// two 8-body segments (8 even).
#define RILBODY(ABS, VC, VN)                                                   \
  {                                                                            \
    const int buf = (ABS) & 1;                                                 \
    if ((ABS) < 15) {                                                          \
      _Pragma("unroll")                                                        \
      for (int lb = 0; lb < 2; ++lb)                                           \
        VN[lb] = *(const uint4*)&votes[((size_t)(gid + ((ABS) + 1) * NGRP_R) * BS \
                                        + bg0 + lb) * (KK / 2) + 4 * ks];      \
    }                                                                          \
    float dv[2];                                                               \
    _Pragma("unroll")                                                          \
    for (int lb = 0; lb < 2; ++lb) {                                           \
      float4 a0 = *(const float4*)&actb[2 * bh + lb][k8];                      \
      float4 a1 = *(const float4*)&actb[2 * bh + lb][k8 + 4];                  \
      float d = bflo(VC[lb].x) * a0.x + bfhi(VC[lb].x) * a0.y                  \
              + bflo(VC[lb].y) * a0.z + bfhi(VC[lb].y) * a0.w                  \
              + bflo(VC[lb].z) * a1.x + bfhi(VC[lb].z) * a1.y                  \
              + bflo(VC[lb].w) * a1.z + bfhi(VC[lb].w) * a1.w;                 \
      d += __shfl_xor(d, 1, 4);                                                \
      d += __shfl_xor(d, 2, 4);                                                \
      dv[lb] = d;                                                              \
    }                                                                          \
    if (j4 == 0) sm[buf][(2 * bh) * 65 + co] = dv[0];                          \
    if (j4 == 1) sm[buf][(2 * bh + 1) * 65 + co] = dv[1];                      \
    WAITLGKM; BAR();                                                           \
    if (t < 256) {                                                             \
      float l0 = sm[buf][(t >> 6) * 65 + (t & 63)];                            \
      float mx = l0;                                                           \
      mx = fmaxf(mx, __shfl_xor(mx, 1, 64));                                   \
      mx = fmaxf(mx, __shfl_xor(mx, 2, 64));                                   \
      mx = fmaxf(mx, __shfl_xor(mx, 4, 64));                                   \
      mx = fmaxf(mx, __shfl_xor(mx, 8, 64));                                   \
      mx = fmaxf(mx, __shfl_xor(mx, 16, 64));                                  \
      mx = fmaxf(mx, __shfl_xor(mx, 32, 64));                                  \
      float e = __expf(l0 - mx);                                               \
      float ssum = e;                                                          \
      ssum += __shfl_xor(ssum, 1, 64);                                         \
      ssum += __shfl_xor(ssum, 2, 64);                                         \
      ssum += __shfl_xor(ssum, 4, 64);                                         \
      ssum += __shfl_xor(ssum, 8, 64);                                         \
      ssum += __shfl_xor(ssum, 16, 64);                                        \
      ssum += __shfl_xor(ssum, 32, 64);                                        \
      sm[buf][(t >> 6) * 65 + (t & 63)] = e / ssum;                            \
      WAITLGKM;                                                                \
    }                                                                          \
    BAR();                                                                     \
    _Pragma("unroll")                                                          \
    for (int lb = 0; lb < 2; ++lb) {                                           \
      float r = sm[buf][(2 * bh + lb) * 65 + co];                              \
      acc[2 * lb + 0].x = fmaf(r, bflo(VC[lb].x), acc[2 * lb + 0].x);          \
      acc[2 * lb + 0].y = fmaf(r, bfhi(VC[lb].x), acc[2 * lb + 0].y);          \
      acc[2 * lb + 0].z = fmaf(r, bflo(VC[lb].y), acc[2 * lb + 0].z);          \
      acc[2 * lb + 0].w = fmaf(r, bfhi(VC[lb].y), acc[2 * lb + 0].w);          \
      acc[2 * lb + 1].x = fmaf(r, bflo(VC[lb].z), acc[2 * lb + 1].x);          \
      acc[2 * lb + 1].y = fmaf(r, bfhi(VC[lb].z), acc[2 * lb + 1].y);          \
      acc[2 * lb + 1].z = fmaf(r, bflo(VC[lb].w), acc[2 * lb + 1].z);          \
      acc[2 * lb + 1].w = fmaf(r, bfhi(VC[lb].w), acc[2 * lb + 1].w);          \
    }                                                                          \
  }

template <bool TWOACT>
__global__ __launch_bounds__(512, 2) void route_kernel(
    const unsigned* __restrict__ votes,   // [CI][BS][KK/2]
    const float* __restrict__ act1,       // [BS][KK]
    const float* __restrict__ act2,       // [BS][KK] (TWOACT only)
    float* __restrict__ partials)         // [NGRP_R][BS][KK]
{
    __shared__ float actb[4][KK];   // 32 KB (act1 or act1+act2)
    __shared__ float sm[2][4 * 65]; // 2 KB, double-buffered per il

    const int t = threadIdx.x;       // 0..511
    const int phys = blockIdx.x;     // 0..511
    const int xcd = phys & 7;
    const int slot = phys >> 3;      // 0..63
    const int gid = xcd * 16 + (slot >> 2);  // 0..127
    const int quarter = slot & 3;    // batches quarter*4 .. +3

    const int ks = t & 255;          // k-slice
    const int k8 = 8 * ks;
    const int co = ks >> 2;
    const int j4 = ks & 3;
    const int bh = t >> 8;           // 0/1: local batch pair
    const int bg0 = quarter * 4 + 2 * bh;

    {   // stage act (sum of two for TWOACT)
        int br = t >> 7, e0 = (t & 127) * 16;
#pragma unroll
        for (int r = 0; r < 4; ++r) {
            float4 u = *(const float4*)&act1[(size_t)(quarter * 4 + br) * KK + e0 + 4 * r];
            if constexpr (TWOACT) {
                float4 u2 = *(const float4*)&act2[(size_t)(quarter * 4 + br) * KK + e0 + 4 * r];
                u.x += u2.x; u.y += u2.y; u.z += u2.z; u.w += u2.w;
            }
            *(float4*)&actb[br][e0 + 4 * r] = u;
        }
    }
    __syncthreads();

    float4 acc[4];
#pragma unroll
    for (int i = 0; i < 4; ++i) acc[i] = make_float4(0.f, 0.f, 0.f, 0.f);

    uint4 vA[2], vB[2];
#pragma unroll
    for (int lb = 0; lb < 2; ++lb)
        vA[lb] = *(const uint4*)&votes[((size_t)gid * BS + bg0 + lb) * (KK / 2) + 4 * ks];

    RILBODY(0,  vA, vB)
    RILBODY(1,  vB, vA)
    RILBODY(2,  vA, vB)
    RILBODY(3,  vB, vA)
    RILBODY(4,  vA, vB)
    RILBODY(5,  vB, vA)
    RILBODY(6,  vA, vB)
    RILBODY(7,  vB, vA)
    RILBODY(8,  vA, vB)
    RILBODY(9,  vB, vA)
    RILBODY(10, vA, vB)
    RILBODY(11, vB, vA)
    RILBODY(12, vA, vB)
    RILBODY(13, vB, vA)
    RILBODY(14, vA, vB)
    RILBODY(15, vB, vA)

#pragma unroll
    for (int lb = 0; lb < 2; ++lb) {
        float* pp = &partials[((size_t)gid * BS + bg0 + lb) * KK + k8];
        *(float4*)pp = acc[2 * lb];
        *(float4*)(pp + 4) = acc[2 * lb + 1];
    }
}

// 256 blocks x 128 threads; 4-way split over G + LDS combine
template <int G>
__global__ __launch_bounds__(128) void reduce_squash(
    const float* __restrict__ partials,   // [G][BS][KK]
    const float* __restrict__ bias,
    float* __restrict__ act_out, float scale)
{
    __shared__ float4 sred[4][32];
    const int t = threadIdx.x;
    const int blk = blockIdx.x;
    const int lane = t & 31;
    const int gp = t >> 5;
    const int o4 = blk * 128 + lane * 4;
    const int b = o4 >> 11;
    const int kk = o4 & (KK - 1);
    const float* p = partials + (size_t)b * KK + kk;
    const size_t stride = (size_t)BS * KK;

    float4 s = make_float4(0.f, 0.f, 0.f, 0.f);
#pragma unroll 4
    for (int g = gp * (G / 4); g < gp * (G / 4) + (G / 4); ++g) {
        float4 v = *(const float4*)(p + (size_t)g * stride);
        s.x += v.x; s.y += v.y; s.z += v.z; s.w += v.w;
    }
    sred[gp][lane] = s;
    __syncthreads();

    if (t < 32) {
        float4 v0 = sred[0][t], v1 = sred[1][t], v2 = sred[2][t], v3 = sred[3][t];
        float4 v;
        v.x = (v0.x + v1.x) + (v2.x + v3.x);
        v.y = (v0.y + v1.y) + (v2.y + v3.y);
        v.z = (v0.z + v1.z) + (v2.z + v3.z);
        v.w = (v0.w + v1.w) + (v2.w + v3.w);
        const int ot = blk * 128 + t * 4;
        float4 bb = *(const float4*)&bias[ot & (KK - 1)];
        v.x = v.x * scale + bb.x;
        v.y = v.y * scale + bb.y;
        v.z = v.z * scale + bb.z;
        v.w = v.w * scale + bb.w;
        float n2 = v.x * v.x + v.y * v.y + v.z * v.z + v.w * v.w;
#pragma unroll
        for (int m = 1; m < 8; m <<= 1) n2 += __shfl_xor(n2, m, 8);
        float norm = sqrtf(n2);
        float sc = norm / (1.f + n2);
        float4 o = make_float4(v.x * sc, v.y * sc, v.z * sc, v.w * sc);
        *(float4*)&act_out[ot] = o;
    }
}

extern "C" void kernel_launch(void* const* d_in, const int* in_sizes, int n_in,
                              void* d_out, int out_size, void* d_ws, size_t ws_size,
                              hipStream_t stream) {
    const float* x = (const float*)d_in[0];
    const float* w = (const float*)d_in[1];
    const float* bias = (const float*)d_in[2];
    float* out = (float*)d_out;

    char* p = (char*)d_ws;
    unsigned* votes = (unsigned*)p; p += (size_t)CI * BS * KK * 2;   // 134 MB (bf16)
    float* partials = (float*)p;    p += (size_t)NGRP * BS * KK * 4; // 33.5 MB
    float* act1 = (float*)p;        p += (size_t)BS * KK * 4;
    float* act2 = (float*)p;

    votes_kernel<<<2 * NGRP, 512, 0, stream>>>(x, w, votes, partials);
    reduce_squash<NGRP><<<256, 128, 0, stream>>>(partials, bias, act1, 1.0f / (float)CO);
    route_kernel<false><<<4 * NGRP_R, 512, 0, stream>>>(votes, act1, nullptr, partials);
    reduce_squash<NGRP_R><<<256, 128, 0, stream>>>(partials, bias, act2, 1.0f);
    route_kernel<true><<<4 * NGRP_R, 512, 0, stream>>>(votes, act1, act2, partials);
    reduce_squash<NGRP_R><<<256, 128, 0, stream>>>(partials, bias, out, 1.0f);
}

// Round 17
// 191.370 us; speedup vs baseline: 1.2342x; 1.2342x over previous
//
#include <hip/hip_runtime.h>

#define BS 16
#define CI 2048
#define NI 16
#define CO 64
#define NO 32
#define KK 2048   // CO*NO
#define NGRP 256  // i-groups

__device__ __forceinline__ void load_lds16(const float* g, float* l) {
    __builtin_amdgcn_global_load_lds(
        (const __attribute__((address_space(1))) void*)g,
        (__attribute__((address_space(3))) void*)l, 16, 0, 0);
}

#define WAITVM12 asm volatile("s_waitcnt vmcnt(12)" ::: "memory")
#define WAITVM4  asm volatile("s_waitcnt vmcnt(4)" ::: "memory")
#define WAITVM0  asm volatile("s_waitcnt vmcnt(0)" ::: "memory")
#define WAITLGKM asm volatile("s_waitcnt lgkmcnt(0)" ::: "memory")
#define BAR __builtin_amdgcn_s_barrier
#define MEMFENCE asm volatile("" ::: "memory")

__device__ __forceinline__ unsigned bf16rne(float f) {
    unsigned u = __float_as_uint(f);
    return (u + 0x7fffu + ((u >> 16) & 1u)) >> 16;
}
__device__ __forceinline__ unsigned pack2(float lo, float hi) {
    return bf16rne(lo) | (bf16rne(hi) << 16);
}
__device__ __forceinline__ float bflo(unsigned u) { return __uint_as_float(u << 16); }
__device__ __forceinline__ float bfhi(unsigned u) { return __uint_as_float(u & 0xffff0000u); }

// ---------------- pass 0: weights -> votes(bf16) + uniform-route sums ------
// FROZEN (r12/r13/r15-proven): 512 thr, lb(512,2) -> 128 VGPR (the only
// allocator point that doesn't spill; min-wave hints trigger spill - r5/r6/r14),
// 512 blocks (sibling pairs share weights via same-XCD L2), self-sliced
// global_load_lds staging, counted vmcnt ledger incl. the 8 vote stores.
__global__ __launch_bounds__(512, 2) void votes_kernel(
    const float* __restrict__ x,      // [BS][CI][NI]
    const float* __restrict__ w,      // [CI][NI][KK]
    unsigned* __restrict__ votes,     // [CI][BS][KK/2] u32 = 2 bf16
    float* __restrict__ partials)     // [NGRP][BS][KK]
{
    __shared__ float wbuf[2][4 * KK]; // 64 KB: double-buffered 4-row quarters
    __shared__ float xb[8][8][NI];    // 4 KB

    const int t = threadIdx.x;
    const int phys = blockIdx.x;
    const int xcd = phys & 7;
    const int slot = phys >> 3;
    const int pairid = xcd * 32 + (slot >> 1);
    const int half = slot & 1;
    const int k4 = 4 * t;

    {
        int il = t >> 6, b = (t >> 3) & 7, n0 = (t & 7) * 2;
        int i = pairid + il * NGRP;
        *(float2*)&xb[il][b][n0] =
            *(const float2*)&x[((size_t)(half * 8 + b) * CI + i) * NI + n0];
    }
    __syncthreads();  // x visible; counters drained: exact ledger starts

    float4 acc[8];
#pragma unroll
    for (int b = 0; b < 8; ++b) acc[b] = make_float4(0.f, 0.f, 0.f, 0.f);

    auto issue = [&](int s) {   // quarter s: capsule s>>2, ni rows 4(s&3)..+3
        int ilp = s >> 2, qp = s & 3;
        const float* gb = w + ((size_t)(pairid + ilp * NGRP) * NI + qp * 4) * KK + k4;
        float* lb = wbuf[s & 1] + k4;
#pragma unroll
        for (int r = 0; r < 4; ++r)
            load_lds16(gb + (size_t)r * KK, lb + r * KK);
    };

    auto computequarter = [&](int il, int q, float4(&dst)[8]) {
#pragma unroll
        for (int rg = 0; rg < 2; ++rg) {
            float4 wA = *(const float4*)&wbuf[q & 1][(2 * rg) * KK + k4];
            float4 wB = *(const float4*)&wbuf[q & 1][(2 * rg + 1) * KK + k4];
#pragma unroll
            for (int b = 0; b < 8; ++b) {
                float2 xv = *(const float2*)&xb[il][b][q * 4 + 2 * rg];
                dst[b].x = fmaf(xv.x, wA.x, dst[b].x);
                dst[b].y = fmaf(xv.x, wA.y, dst[b].y);
                dst[b].z = fmaf(xv.x, wA.z, dst[b].z);
                dst[b].w = fmaf(xv.x, wA.w, dst[b].w);
                dst[b].x = fmaf(xv.y, wB.x, dst[b].x);
                dst[b].y = fmaf(xv.y, wB.y, dst[b].y);
                dst[b].z = fmaf(xv.y, wB.z, dst[b].z);
                dst[b].w = fmaf(xv.y, wB.w, dst[b].w);
            }
        }
    };

    issue(0); issue(1);

#pragma unroll 1
    for (int il = 0; il < 8; ++il) {
        float4 v[8];
#pragma unroll
        for (int b = 0; b < 8; ++b) v[b] = make_float4(0.f, 0.f, 0.f, 0.f);

#pragma unroll
        for (int q = 0; q < 4; ++q) {
            if (q < 2) { if (il > 0) { WAITVM12; } else { WAITVM4; } }
            else if (q == 3) { if (il == 7) { WAITVM0; } else { WAITVM4; } }
            else { WAITVM4; }
            computequarter(il, q, v);
            WAITLGKM;
            if (il < 7 || q < 2) issue(il * 4 + q + 2);
        }

        const size_t vbase = ((size_t)(pairid + il * NGRP) * BS + half * 8) * (KK / 2) + 2 * t;
#pragma unroll
        for (int b = 0; b < 8; ++b) {
            acc[b].x += v[b].x; acc[b].y += v[b].y;
            acc[b].z += v[b].z; acc[b].w += v[b].w;
            uint2 pk;
            pk.x = pack2(v[b].x, v[b].y);
            pk.y = pack2(v[b].z, v[b].w);
            *(uint2*)&votes[vbase + (size_t)b * (KK / 2)] = pk;
        }
        MEMFENCE;
    }

#pragma unroll
    for (int b = 0; b < 8; ++b)
        *(float4*)&partials[((size_t)pairid * BS + half * 8 + b) * KK + k4] = acc[b];
}

// ---------------- routing from bf16 votes (r13 structure, no logits) -------
// Linearity: iter-3 logits = v.act1 + v.act2 = v.(act1+act2), so route2 is
// route1 with actb = act1+act2. Zero logits traffic, no lg registers.
#define RILBODY(IL, VC, VN)                                                    \
  {                                                                            \
    const int buf = (IL) & 1;                                                  \
    if ((IL) < 7) {                                                            \
      _Pragma("unroll")                                                        \
      for (int lb = 0; lb < 2; ++lb)                                           \
        VN[lb] = *(const uint4*)&votes[((size_t)(gid + ((IL) + 1) * NGRP) * BS \
                                        + bg0 + lb) * (KK / 2) + 4 * ks];      \
    }                                                                          \
    float dv[2];                                                               \
    _Pragma("unroll")                                                          \
    for (int lb = 0; lb < 2; ++lb) {                                           \
      float4 a0 = *(const float4*)&actb[2 * bh + lb][k8];                      \
      float4 a1 = *(const float4*)&actb[2 * bh + lb][k8 + 4];                  \
      float d = bflo(VC[lb].x) * a0.x + bfhi(VC[lb].x) * a0.y                  \
              + bflo(VC[lb].y) * a0.z + bfhi(VC[lb].y) * a0.w                  \
              + bflo(VC[lb].z) * a1.x + bfhi(VC[lb].z) * a1.y                  \
              + bflo(VC[lb].w) * a1.z + bfhi(VC[lb].w) * a1.w;                 \
      d += __shfl_xor(d, 1, 4);                                                \
      d += __shfl_xor(d, 2, 4);                                                \
      dv[lb] = d;                                                              \
    }                                                                          \
    if (j4 == 0) sm[buf][(2 * bh) * 65 + co] = dv[0];                          \
    if (j4 == 1) sm[buf][(2 * bh + 1) * 65 + co] = dv[1];                      \
    WAITLGKM; BAR();                                                           \
    if (t < 256) {                                                             \
      float l0 = sm[buf][(t >> 6) * 65 + (t & 63)];                            \
      float mx = l0;                                                           \
      mx = fmaxf(mx, __shfl_xor(mx, 1, 64));                                   \
      mx = fmaxf(mx, __shfl_xor(mx, 2, 64));                                   \
      mx = fmaxf(mx, __shfl_xor(mx, 4, 64));                                   \
      mx = fmaxf(mx, __shfl_xor(mx, 8, 64));                                   \
      mx = fmaxf(mx, __shfl_xor(mx, 16, 64));                                  \
      mx = fmaxf(mx, __shfl_xor(mx, 32, 64));                                  \
      float e = __expf(l0 - mx);                                               \
      float ssum = e;                                                          \
      ssum += __shfl_xor(ssum, 1, 64);                                         \
      ssum += __shfl_xor(ssum, 2, 64);                                         \
      ssum += __shfl_xor(ssum, 4, 64);                                         \
      ssum += __shfl_xor(ssum, 8, 64);                                         \
      ssum += __shfl_xor(ssum, 16, 64);                                        \
      ssum += __shfl_xor(ssum, 32, 64);                                        \
      sm[buf][(t >> 6) * 65 + (t & 63)] = e / ssum;                            \
      WAITLGKM;                                                                \
    }                                                                          \
    BAR();                                                                     \
    _Pragma("unroll")                                                          \
    for (int lb = 0; lb < 2; ++lb) {                                           \
      float r = sm[buf][(2 * bh + lb) * 65 + co];                              \
      acc[2 * lb + 0].x = fmaf(r, bflo(VC[lb].x), acc[2 * lb + 0].x);          \
      acc[2 * lb + 0].y = fmaf(r, bfhi(VC[lb].x), acc[2 * lb + 0].y);          \
      acc[2 * lb + 0].z = fmaf(r, bflo(VC[lb].y), acc[2 * lb + 0].z);          \
      acc[2 * lb + 0].w = fmaf(r, bfhi(VC[lb].y), acc[2 * lb + 0].w);          \
      acc[2 * lb + 1].x = fmaf(r, bflo(VC[lb].z), acc[2 * lb + 1].x);          \
      acc[2 * lb + 1].y = fmaf(r, bfhi(VC[lb].z), acc[2 * lb + 1].y);          \
      acc[2 * lb + 1].z = fmaf(r, bflo(VC[lb].w), acc[2 * lb + 1].z);          \
      acc[2 * lb + 1].w = fmaf(r, bfhi(VC[lb].w), acc[2 * lb + 1].w);          \
    }                                                                          \
  }

template <bool TWOACT>
__global__ __launch_bounds__(512, 2) void route_kernel(
    const unsigned* __restrict__ votes,   // [CI][BS][KK/2]
    const float* __restrict__ act1,       // [BS][KK]
    const float* __restrict__ act2,       // [BS][KK] (TWOACT only)
    float* __restrict__ partials)         // [NGRP][BS][KK]
{
    __shared__ float actb[4][KK];   // 32 KB (act1 or act1+act2)
    __shared__ float sm[2][4 * 65]; // 2 KB, double-buffered per il

    const int t = threadIdx.x;       // 0..511
    const int phys = blockIdx.x;     // 0..1023
    const int xcd = phys & 7;
    const int slot = phys >> 3;      // 0..127
    const int gid = xcd * 32 + (slot >> 2);  // 0..255
    const int quarter = slot & 3;    // batches quarter*4 .. +3

    const int ks = t & 255;          // k-slice
    const int k8 = 8 * ks;
    const int co = ks >> 2;
    const int j4 = ks & 3;
    const int bh = t >> 8;           // 0/1: local batch pair
    const int bg0 = quarter * 4 + 2 * bh;

    {   // stage act (sum of two for TWOACT)
        int br = t >> 7, e0 = (t & 127) * 16;
#pragma unroll
        for (int r = 0; r < 4; ++r) {
            float4 u = *(const float4*)&act1[(size_t)(quarter * 4 + br) * KK + e0 + 4 * r];
            if constexpr (TWOACT) {
                float4 u2 = *(const float4*)&act2[(size_t)(quarter * 4 + br) * KK + e0 + 4 * r];
                u.x += u2.x; u.y += u2.y; u.z += u2.z; u.w += u2.w;
            }
            *(float4*)&actb[br][e0 + 4 * r] = u;
        }
    }
    __syncthreads();

    float4 acc[4];
#pragma unroll
    for (int i = 0; i < 4; ++i) acc[i] = make_float4(0.f, 0.f, 0.f, 0.f);

    uint4 vA[2], vB[2];
#pragma unroll
    for (int lb = 0; lb < 2; ++lb)
        vA[lb] = *(const uint4*)&votes[((size_t)gid * BS + bg0 + lb) * (KK / 2) + 4 * ks];

    RILBODY(0, vA, vB)
    RILBODY(1, vB, vA)
    RILBODY(2, vA, vB)
    RILBODY(3, vB, vA)
    RILBODY(4, vA, vB)
    RILBODY(5, vB, vA)
    RILBODY(6, vA, vB)
    RILBODY(7, vB, vA)

#pragma unroll
    for (int lb = 0; lb < 2; ++lb) {
        float* pp = &partials[((size_t)gid * BS + bg0 + lb) * KK + k8];
        *(float4*)pp = acc[2 * lb];
        *(float4*)(pp + 4) = acc[2 * lb + 1];
    }
}

// 256 blocks x 128 threads; 4-way split over NGRP + LDS combine
__global__ __launch_bounds__(128) void reduce_squash(
    const float* __restrict__ partials,   // [NGRP][BS][KK]
    const float* __restrict__ bias,
    float* __restrict__ act_out, float scale)
{
    __shared__ float4 sred[4][32];
    const int t = threadIdx.x;
    const int blk = blockIdx.x;
    const int lane = t & 31;
    const int gp = t >> 5;
    const int o4 = blk * 128 + lane * 4;
    const int b = o4 >> 11;
    const int kk = o4 & (KK - 1);
    const float* p = partials + (size_t)b * KK + kk;
    const size_t stride = (size_t)BS * KK;

    float4 s = make_float4(0.f, 0.f, 0.f, 0.f);
#pragma unroll 4
    for (int g = gp * 64; g < gp * 64 + 64; ++g) {
        float4 v = *(const float4*)(p + (size_t)g * stride);
        s.x += v.x; s.y += v.y; s.z += v.z; s.w += v.w;
    }
    sred[gp][lane] = s;
    __syncthreads();

    if (t < 32) {
        float4 v0 = sred[0][t], v1 = sred[1][t], v2 = sred[2][t], v3 = sred[3][t];
        float4 v;
        v.x = (v0.x + v1.x) + (v2.x + v3.x);
        v.y = (v0.y + v1.y) + (v2.y + v3.y);
        v.z = (v0.z + v1.z) + (v2.z + v3.z);
        v.w = (v0.w + v1.w) + (v2.w + v3.w);
        const int ot = blk * 128 + t * 4;
        float4 bb = *(const float4*)&bias[ot & (KK - 1)];
        v.x = v.x * scale + bb.x;
        v.y = v.y * scale + bb.y;
        v.z = v.z * scale + bb.z;
        v.w = v.w * scale + bb.w;
        float n2 = v.x * v.x + v.y * v.y + v.z * v.z + v.w * v.w;
#pragma unroll
        for (int m = 1; m < 8; m <<= 1) n2 += __shfl_xor(n2, m, 8);
        float norm = sqrtf(n2);
        float sc = norm / (1.f + n2);
        float4 o = make_float4(v.x * sc, v.y * sc, v.z * sc, v.w * sc);
        *(float4*)&act_out[ot] = o;
    }
}

extern "C" void kernel_launch(void* const* d_in, const int* in_sizes, int n_in,
                              void* d_out, int out_size, void* d_ws, size_t ws_size,
                              hipStream_t stream) {
    const float* x = (const float*)d_in[0];
    const float* w = (const float*)d_in[1];
    const float* bias = (const float*)d_in[2];
    float* out = (float*)d_out;

    char* p = (char*)d_ws;
    unsigned* votes = (unsigned*)p; p += (size_t)CI * BS * KK * 2;   // 134 MB (bf16)
    float* partials = (float*)p;    p += (size_t)NGRP * BS * KK * 4; // 33.5 MB
    float* act1 = (float*)p;        p += (size_t)BS * KK * 4;
    float* act2 = (float*)p;

    votes_kernel<<<2 * NGRP, 512, 0, stream>>>(x, w, votes, partials);
    reduce_squash<<<256, 128, 0, stream>>>(partials, bias, act1, 1.0f / (float)CO);
    route_kernel<false><<<4 * NGRP, 512, 0, stream>>>(votes, act1, nullptr, partials);
    reduce_squash<<<256, 128, 0, stream>>>(partials, bias, act2, 1.0f);
    route_kernel<true><<<4 * NGRP, 512, 0, stream>>>(votes, act1, act2, partials);
    reduce_squash<<<256, 128, 0, stream>>>(partials, bias, out, 1.0f);
}

// Round 18
// 187.569 us; speedup vs baseline: 1.2592x; 1.0203x over previous
//
#include <hip/hip_runtime.h>

#define BS 16
#define CI 2048
#define NI 16
#define CO 64
#define NO 32
#define KK 2048   // CO*NO
#define NGRP 256  // i-groups

__device__ __forceinline__ void load_lds16(const float* g, float* l) {
    __builtin_amdgcn_global_load_lds(
        (const __attribute__((address_space(1))) void*)g,
        (__attribute__((address_space(3))) void*)l, 16, 0, 0);
}

#define WAITVM12 asm volatile("s_waitcnt vmcnt(12)" ::: "memory")
#define WAITVM4  asm volatile("s_waitcnt vmcnt(4)" ::: "memory")
#define WAITVM0  asm volatile("s_waitcnt vmcnt(0)" ::: "memory")
#define WAITLGKM asm volatile("s_waitcnt lgkmcnt(0)" ::: "memory")
#define BAR __builtin_amdgcn_s_barrier
#define MEMFENCE asm volatile("" ::: "memory")

__device__ __forceinline__ unsigned bf16rne(float f) {
    unsigned u = __float_as_uint(f);
    return (u + 0x7fffu + ((u >> 16) & 1u)) >> 16;
}
__device__ __forceinline__ unsigned pack2(float lo, float hi) {
    return bf16rne(lo) | (bf16rne(hi) << 16);
}
__device__ __forceinline__ float bflo(unsigned u) { return __uint_as_float(u << 16); }
__device__ __forceinline__ float bfhi(unsigned u) { return __uint_as_float(u & 0xffff0000u); }

// ---------------- pass 0: weights -> votes(bf16) + uniform-route sums ------
// FROZEN (r12/r13/r15/r17-proven): 512 thr, lb(512,2) -> 128 VGPR (the only
// allocator point that doesn't spill; min-wave hints trigger spill - r5/r6/r14),
// 512 blocks (sibling pairs share weights via same-XCD L2), self-sliced
// global_load_lds staging, counted vmcnt ledger incl. the 8 vote stores.
__global__ __launch_bounds__(512, 2) void votes_kernel(
    const float* __restrict__ x,      // [BS][CI][NI]
    const float* __restrict__ w,      // [CI][NI][KK]
    unsigned* __restrict__ votes,     // [CI][BS][KK/2] u32 = 2 bf16
    float* __restrict__ partials)     // [NGRP][BS][KK] (f32 - iter1 path frozen)
{
    __shared__ float wbuf[2][4 * KK]; // 64 KB: double-buffered 4-row quarters
    __shared__ float xb[8][8][NI];    // 4 KB

    const int t = threadIdx.x;
    const int phys = blockIdx.x;
    const int xcd = phys & 7;
    const int slot = phys >> 3;
    const int pairid = xcd * 32 + (slot >> 1);
    const int half = slot & 1;
    const int k4 = 4 * t;

    {
        int il = t >> 6, b = (t >> 3) & 7, n0 = (t & 7) * 2;
        int i = pairid + il * NGRP;
        *(float2*)&xb[il][b][n0] =
            *(const float2*)&x[((size_t)(half * 8 + b) * CI + i) * NI + n0];
    }
    __syncthreads();  // x visible; counters drained: exact ledger starts

    float4 acc[8];
#pragma unroll
    for (int b = 0; b < 8; ++b) acc[b] = make_float4(0.f, 0.f, 0.f, 0.f);

    auto issue = [&](int s) {   // quarter s: capsule s>>2, ni rows 4(s&3)..+3
        int ilp = s >> 2, qp = s & 3;
        const float* gb = w + ((size_t)(pairid + ilp * NGRP) * NI + qp * 4) * KK + k4;
        float* lb = wbuf[s & 1] + k4;
#pragma unroll
        for (int r = 0; r < 4; ++r)
            load_lds16(gb + (size_t)r * KK, lb + r * KK);
    };

    auto computequarter = [&](int il, int q, float4(&dst)[8]) {
#pragma unroll
        for (int rg = 0; rg < 2; ++rg) {
            float4 wA = *(const float4*)&wbuf[q & 1][(2 * rg) * KK + k4];
            float4 wB = *(const float4*)&wbuf[q & 1][(2 * rg + 1) * KK + k4];
#pragma unroll
            for (int b = 0; b < 8; ++b) {
                float2 xv = *(const float2*)&xb[il][b][q * 4 + 2 * rg];
                dst[b].x = fmaf(xv.x, wA.x, dst[b].x);
                dst[b].y = fmaf(xv.x, wA.y, dst[b].y);
                dst[b].z = fmaf(xv.x, wA.z, dst[b].z);
                dst[b].w = fmaf(xv.x, wA.w, dst[b].w);
                dst[b].x = fmaf(xv.y, wB.x, dst[b].x);
                dst[b].y = fmaf(xv.y, wB.y, dst[b].y);
                dst[b].z = fmaf(xv.y, wB.z, dst[b].z);
                dst[b].w = fmaf(xv.y, wB.w, dst[b].w);
            }
        }
    };

    issue(0); issue(1);

#pragma unroll 1
    for (int il = 0; il < 8; ++il) {
        float4 v[8];
#pragma unroll
        for (int b = 0; b < 8; ++b) v[b] = make_float4(0.f, 0.f, 0.f, 0.f);

#pragma unroll
        for (int q = 0; q < 4; ++q) {
            if (q < 2) { if (il > 0) { WAITVM12; } else { WAITVM4; } }
            else if (q == 3) { if (il == 7) { WAITVM0; } else { WAITVM4; } }
            else { WAITVM4; }
            computequarter(il, q, v);
            WAITLGKM;
            if (il < 7 || q < 2) issue(il * 4 + q + 2);
        }

        const size_t vbase = ((size_t)(pairid + il * NGRP) * BS + half * 8) * (KK / 2) + 2 * t;
#pragma unroll
        for (int b = 0; b < 8; ++b) {
            acc[b].x += v[b].x; acc[b].y += v[b].y;
            acc[b].z += v[b].z; acc[b].w += v[b].w;
            uint2 pk;
            pk.x = pack2(v[b].x, v[b].y);
            pk.y = pack2(v[b].z, v[b].w);
            *(uint2*)&votes[vbase + (size_t)b * (KK / 2)] = pk;
        }
        MEMFENCE;
    }

#pragma unroll
    for (int b = 0; b < 8; ++b)
        *(float4*)&partials[((size_t)pairid * BS + half * 8 + b) * KK + k4] = acc[b];
}

// ---------------- routing from bf16 votes (r13/r15 structure) --------------
// Linearity: iter-3 logits = v.act1 + v.act2 = v.(act1+act2), so route2 is
// route1 with actb = act1+act2. NEW r18: partials stored as packed bf16
// (uint4 = 8 bf16 per lb) -> halves route WRITE + reduce FETCH. Structure
// (grid/occupancy/barriers) unchanged from the proven 191-us config.
#define RILBODY(IL, VC, VN)                                                    \
  {                                                                            \
    const int buf = (IL) & 1;                                                  \
    if ((IL) < 7) {                                                            \
      _Pragma("unroll")                                                        \
      for (int lb = 0; lb < 2; ++lb)                                           \
        VN[lb] = *(const uint4*)&votes[((size_t)(gid + ((IL) + 1) * NGRP) * BS \
                                        + bg0 + lb) * (KK / 2) + 4 * ks];      \
    }                                                                          \
    float dv[2];                                                               \
    _Pragma("unroll")                                                          \
    for (int lb = 0; lb < 2; ++lb) {                                           \
      float4 a0 = *(const float4*)&actb[2 * bh + lb][k8];                      \
      float4 a1 = *(const float4*)&actb[2 * bh + lb][k8 + 4];                  \
      float d = bflo(VC[lb].x) * a0.x + bfhi(VC[lb].x) * a0.y                  \
              + bflo(VC[lb].y) * a0.z + bfhi(VC[lb].y) * a0.w                  \
              + bflo(VC[lb].z) * a1.x + bfhi(VC[lb].z) * a1.y                  \
              + bflo(VC[lb].w) * a1.z + bfhi(VC[lb].w) * a1.w;                 \
      d += __shfl_xor(d, 1, 4);                                                \
      d += __shfl_xor(d, 2, 4);                                                \
      dv[lb] = d;                                                              \
    }                                                                          \
    if (j4 == 0) sm[buf][(2 * bh) * 65 + co] = dv[0];                          \
    if (j4 == 1) sm[buf][(2 * bh + 1) * 65 + co] = dv[1];                      \
    WAITLGKM; BAR();                                                           \
    if (t < 256) {                                                             \
      float l0 = sm[buf][(t >> 6) * 65 + (t & 63)];                            \
      float mx = l0;                                                           \
      mx = fmaxf(mx, __shfl_xor(mx, 1, 64));                                   \
      mx = fmaxf(mx, __shfl_xor(mx, 2, 64));                                   \
      mx = fmaxf(mx, __shfl_xor(mx, 4, 64));                                   \
      mx = fmaxf(mx, __shfl_xor(mx, 8, 64));                                   \
      mx = fmaxf(mx, __shfl_xor(mx, 16, 64));                                  \
      mx = fmaxf(mx, __shfl_xor(mx, 32, 64));                                  \
      float e = __expf(l0 - mx);                                               \
      float ssum = e;                                                          \
      ssum += __shfl_xor(ssum, 1, 64);                                         \
      ssum += __shfl_xor(ssum, 2, 64);                                         \
      ssum += __shfl_xor(ssum, 4, 64);                                         \
      ssum += __shfl_xor(ssum, 8, 64);                                         \
      ssum += __shfl_xor(ssum, 16, 64);                                        \
      ssum += __shfl_xor(ssum, 32, 64);                                        \
      sm[buf][(t >> 6) * 65 + (t & 63)] = e / ssum;                            \
      WAITLGKM;                                                                \
    }                                                                          \
    BAR();                                                                     \
    _Pragma("unroll")                                                          \
    for (int lb = 0; lb < 2; ++lb) {                                           \
      float r = sm[buf][(2 * bh + lb) * 65 + co];                              \
      acc[2 * lb + 0].x = fmaf(r, bflo(VC[lb].x), acc[2 * lb + 0].x);          \
      acc[2 * lb + 0].y = fmaf(r, bfhi(VC[lb].x), acc[2 * lb + 0].y);          \
      acc[2 * lb + 0].z = fmaf(r, bflo(VC[lb].y), acc[2 * lb + 0].z);          \
      acc[2 * lb + 0].w = fmaf(r, bfhi(VC[lb].y), acc[2 * lb + 0].w);          \
      acc[2 * lb + 1].x = fmaf(r, bflo(VC[lb].z), acc[2 * lb + 1].x);          \
      acc[2 * lb + 1].y = fmaf(r, bfhi(VC[lb].z), acc[2 * lb + 1].y);          \
      acc[2 * lb + 1].z = fmaf(r, bflo(VC[lb].w), acc[2 * lb + 1].z);          \
      acc[2 * lb + 1].w = fmaf(r, bfhi(VC[lb].w), acc[2 * lb + 1].w);          \
    }                                                                          \
  }

template <bool TWOACT>
__global__ __launch_bounds__(512, 2) void route_kernel(
    const unsigned* __restrict__ votes,   // [CI][BS][KK/2]
    const float* __restrict__ act1,       // [BS][KK]
    const float* __restrict__ act2,       // [BS][KK] (TWOACT only)
    unsigned* __restrict__ partials_bf)   // [NGRP][BS][KK/2] packed bf16
{
    __shared__ float actb[4][KK];   // 32 KB (act1 or act1+act2)
    __shared__ float sm[2][4 * 65]; // 2 KB, double-buffered per il

    const int t = threadIdx.x;       // 0..511
    const int phys = blockIdx.x;     // 0..1023
    const int xcd = phys & 7;
    const int slot = phys >> 3;      // 0..127
    const int gid = xcd * 32 + (slot >> 2);  // 0..255
    const int quarter = slot & 3;    // batches quarter*4 .. +3

    const int ks = t & 255;          // k-slice
    const int k8 = 8 * ks;
    const int co = ks >> 2;
    const int j4 = ks & 3;
    const int bh = t >> 8;           // 0/1: local batch pair
    const int bg0 = quarter * 4 + 2 * bh;

    {   // stage act (sum of two for TWOACT)
        int br = t >> 7, e0 = (t & 127) * 16;
#pragma unroll
        for (int r = 0; r < 4; ++r) {
            float4 u = *(const float4*)&act1[(size_t)(quarter * 4 + br) * KK + e0 + 4 * r];
            if constexpr (TWOACT) {
                float4 u2 = *(const float4*)&act2[(size_t)(quarter * 4 + br) * KK + e0 + 4 * r];
                u.x += u2.x; u.y += u2.y; u.z += u2.z; u.w += u2.w;
            }
            *(float4*)&actb[br][e0 + 4 * r] = u;
        }
    }
    __syncthreads();

    float4 acc[4];
#pragma unroll
    for (int i = 0; i < 4; ++i) acc[i] = make_float4(0.f, 0.f, 0.f, 0.f);

    uint4 vA[2], vB[2];
#pragma unroll
    for (int lb = 0; lb < 2; ++lb)
        vA[lb] = *(const uint4*)&votes[((size_t)gid * BS + bg0 + lb) * (KK / 2) + 4 * ks];

    RILBODY(0, vA, vB)
    RILBODY(1, vB, vA)
    RILBODY(2, vA, vB)
    RILBODY(3, vB, vA)
    RILBODY(4, vA, vB)
    RILBODY(5, vB, vA)
    RILBODY(6, vA, vB)
    RILBODY(7, vB, vA)

#pragma unroll
    for (int lb = 0; lb < 2; ++lb) {
        uint4 pk;
        pk.x = pack2(acc[2 * lb + 0].x, acc[2 * lb + 0].y);
        pk.y = pack2(acc[2 * lb + 0].z, acc[2 * lb + 0].w);
        pk.z = pack2(acc[2 * lb + 1].x, acc[2 * lb + 1].y);
        pk.w = pack2(acc[2 * lb + 1].z, acc[2 * lb + 1].w);
        *(uint4*)&partials_bf[((size_t)gid * BS + bg0 + lb) * (KK / 2) + 4 * ks] = pk;
    }
}

// f32 reduce (iter1 path, frozen): 256 blocks x 128 thr, 4-way split + LDS
__global__ __launch_bounds__(128) void reduce_squash(
    const float* __restrict__ partials,   // [NGRP][BS][KK]
    const float* __restrict__ bias,
    float* __restrict__ act_out, float scale)
{
    __shared__ float4 sred[4][32];
    const int t = threadIdx.x;
    const int blk = blockIdx.x;
    const int lane = t & 31;
    const int gp = t >> 5;
    const int o4 = blk * 128 + lane * 4;
    const int b = o4 >> 11;
    const int kk = o4 & (KK - 1);
    const float* p = partials + (size_t)b * KK + kk;
    const size_t stride = (size_t)BS * KK;

    float4 s = make_float4(0.f, 0.f, 0.f, 0.f);
#pragma unroll 4
    for (int g = gp * 64; g < gp * 64 + 64; ++g) {
        float4 v = *(const float4*)(p + (size_t)g * stride);
        s.x += v.x; s.y += v.y; s.z += v.z; s.w += v.w;
    }
    sred[gp][lane] = s;
    __syncthreads();

    if (t < 32) {
        float4 v0 = sred[0][t], v1 = sred[1][t], v2 = sred[2][t], v3 = sred[3][t];
        float4 v;
        v.x = (v0.x + v1.x) + (v2.x + v3.x);
        v.y = (v0.y + v1.y) + (v2.y + v3.y);
        v.z = (v0.z + v1.z) + (v2.z + v3.z);
        v.w = (v0.w + v1.w) + (v2.w + v3.w);
        const int ot = blk * 128 + t * 4;
        float4 bb = *(const float4*)&bias[ot & (KK - 1)];
        v.x = v.x * scale + bb.x;
        v.y = v.y * scale + bb.y;
        v.z = v.z * scale + bb.z;
        v.w = v.w * scale + bb.w;
        float n2 = v.x * v.x + v.y * v.y + v.z * v.z + v.w * v.w;
#pragma unroll
        for (int m = 1; m < 8; m <<= 1) n2 += __shfl_xor(n2, m, 8);
        float norm = sqrtf(n2);
        float sc = norm / (1.f + n2);
        float4 o = make_float4(v.x * sc, v.y * sc, v.z * sc, v.w * sc);
        *(float4*)&act_out[ot] = o;
    }
}

// bf16 reduce (route paths): same structure, uint2 (4 bf16) loads per g
__global__ __launch_bounds__(128) void reduce_squash_bf(
    const unsigned* __restrict__ partials_bf,  // [NGRP][BS][KK/2]
    const float* __restrict__ bias,
    float* __restrict__ act_out)
{
    __shared__ float4 sred[4][32];
    const int t = threadIdx.x;
    const int blk = blockIdx.x;
    const int lane = t & 31;
    const int gp = t >> 5;
    const int o4 = blk * 128 + lane * 4;
    const int b = o4 >> 11;
    const int kk = o4 & (KK - 1);
    const unsigned* p = partials_bf + (size_t)b * (KK / 2) + kk / 2;
    const size_t stride = (size_t)BS * (KK / 2);

    float4 s = make_float4(0.f, 0.f, 0.f, 0.f);
#pragma unroll 4
    for (int g = gp * 64; g < gp * 64 + 64; ++g) {
        uint2 u = *(const uint2*)(p + (size_t)g * stride);
        s.x += bflo(u.x); s.y += bfhi(u.x);
        s.z += bflo(u.y); s.w += bfhi(u.y);
    }
    sred[gp][lane] = s;
    __syncthreads();

    if (t < 32) {
        float4 v0 = sred[0][t], v1 = sred[1][t], v2 = sred[2][t], v3 = sred[3][t];
        float4 v;
        v.x = (v0.x + v1.x) + (v2.x + v3.x);
        v.y = (v0.y + v1.y) + (v2.y + v3.y);
        v.z = (v0.z + v1.z) + (v2.z + v3.z);
        v.w = (v0.w + v1.w) + (v2.w + v3.w);
        const int ot = blk * 128 + t * 4;
        float4 bb = *(const float4*)&bias[ot & (KK - 1)];
        v.x += bb.x; v.y += bb.y; v.z += bb.z; v.w += bb.w;
        float n2 = v.x * v.x + v.y * v.y + v.z * v.z + v.w * v.w;
#pragma unroll
        for (int m = 1; m < 8; m <<= 1) n2 += __shfl_xor(n2, m, 8);
        float norm = sqrtf(n2);
        float sc = norm / (1.f + n2);
        float4 o = make_float4(v.x * sc, v.y * sc, v.z * sc, v.w * sc);
        *(float4*)&act_out[ot] = o;
    }
}

extern "C" void kernel_launch(void* const* d_in, const int* in_sizes, int n_in,
                              void* d_out, int out_size, void* d_ws, size_t ws_size,
                              hipStream_t stream) {
    const float* x = (const float*)d_in[0];
    const float* w = (const float*)d_in[1];
    const float* bias = (const float*)d_in[2];
    float* out = (float*)d_out;

    char* p = (char*)d_ws;
    unsigned* votes = (unsigned*)p;       p += (size_t)CI * BS * KK * 2;   // 134 MB (bf16)
    float* partials = (float*)p;          p += (size_t)NGRP * BS * KK * 4; // 33.5 MB (f32)
    unsigned* partials_bf = (unsigned*)p; p += (size_t)NGRP * BS * KK * 2; // 16.8 MB (bf16)
    float* act1 = (float*)p;              p += (size_t)BS * KK * 4;
    float* act2 = (float*)p;

    votes_kernel<<<2 * NGRP, 512, 0, stream>>>(x, w, votes, partials);
    reduce_squash<<<256, 128, 0, stream>>>(partials, bias, act1, 1.0f / (float)CO);
    route_kernel<false><<<4 * NGRP, 512, 0, stream>>>(votes, act1, nullptr, partials_bf);
    reduce_squash_bf<<<256, 128, 0, stream>>>(partials_bf, bias, act2);
    route_kernel<true><<<4 * NGRP, 512, 0, stream>>>(votes, act1, act2, partials_bf);
    reduce_squash_bf<<<256, 128, 0, stream>>>(partials_bf, bias, out);
}

// Round 19
// 180.749 us; speedup vs baseline: 1.3067x; 1.0377x over previous
//
#include <hip/hip_runtime.h>

#define BS 16
#define CI 2048
#define NI 16
#define CO 64
#define NO 32
#define KK 2048   // CO*NO
#define NGRP 256  // i-groups

__device__ __forceinline__ void load_lds16(const float* g, float* l) {
    __builtin_amdgcn_global_load_lds(
        (const __attribute__((address_space(1))) void*)g,
        (__attribute__((address_space(3))) void*)l, 16, 0, 0);
}

#define WAITVM12 asm volatile("s_waitcnt vmcnt(12)" ::: "memory")
#define WAITVM4  asm volatile("s_waitcnt vmcnt(4)" ::: "memory")
#define WAITVM0  asm volatile("s_waitcnt vmcnt(0)" ::: "memory")
#define WAITLGKM asm volatile("s_waitcnt lgkmcnt(0)" ::: "memory")
#define BAR __builtin_amdgcn_s_barrier
#define MEMFENCE asm volatile("" ::: "memory")

__device__ __forceinline__ unsigned bf16rne(float f) {
    unsigned u = __float_as_uint(f);
    return (u + 0x7fffu + ((u >> 16) & 1u)) >> 16;
}
__device__ __forceinline__ unsigned pack2(float lo, float hi) {
    return bf16rne(lo) | (bf16rne(hi) << 16);
}
__device__ __forceinline__ float bflo(unsigned u) { return __uint_as_float(u << 16); }
__device__ __forceinline__ float bfhi(unsigned u) { return __uint_as_float(u & 0xffff0000u); }

// ---------------- pass 0: weights -> votes(bf16) + uniform-route sums ------
// FROZEN structure (r12/r13/r15/r17-proven): 512 thr, lb(512,2) -> 128 VGPR
// (the only allocator point that doesn't spill; min-wave hints trigger spill
// - r5/r6/r14), 512 blocks (sibling pairs share weights via same-XCD L2),
// self-sliced global_load_lds staging, counted vmcnt ledger incl. the 8 vote
// stores. r19: epilogue partials now packed bf16 (post-ledger, zero
// structural impact) -> -33.5 MB round trip.
__global__ __launch_bounds__(512, 2) void votes_kernel(
    const float* __restrict__ x,      // [BS][CI][NI]
    const float* __restrict__ w,      // [CI][NI][KK]
    unsigned* __restrict__ votes,     // [CI][BS][KK/2] u32 = 2 bf16
    unsigned* __restrict__ partials_bf) // [NGRP][BS][KK/2] packed bf16
{
    __shared__ float wbuf[2][4 * KK]; // 64 KB: double-buffered 4-row quarters
    __shared__ float xb[8][8][NI];    // 4 KB

    const int t = threadIdx.x;
    const int phys = blockIdx.x;
    const int xcd = phys & 7;
    const int slot = phys >> 3;
    const int pairid = xcd * 32 + (slot >> 1);
    const int half = slot & 1;
    const int k4 = 4 * t;

    {
        int il = t >> 6, b = (t >> 3) & 7, n0 = (t & 7) * 2;
        int i = pairid + il * NGRP;
        *(float2*)&xb[il][b][n0] =
            *(const float2*)&x[((size_t)(half * 8 + b) * CI + i) * NI + n0];
    }
    __syncthreads();  // x visible; counters drained: exact ledger starts

    float4 acc[8];
#pragma unroll
    for (int b = 0; b < 8; ++b) acc[b] = make_float4(0.f, 0.f, 0.f, 0.f);

    auto issue = [&](int s) {   // quarter s: capsule s>>2, ni rows 4(s&3)..+3
        int ilp = s >> 2, qp = s & 3;
        const float* gb = w + ((size_t)(pairid + ilp * NGRP) * NI + qp * 4) * KK + k4;
        float* lb = wbuf[s & 1] + k4;
#pragma unroll
        for (int r = 0; r < 4; ++r)
            load_lds16(gb + (size_t)r * KK, lb + r * KK);
    };

    auto computequarter = [&](int il, int q, float4(&dst)[8]) {
#pragma unroll
        for (int rg = 0; rg < 2; ++rg) {
            float4 wA = *(const float4*)&wbuf[q & 1][(2 * rg) * KK + k4];
            float4 wB = *(const float4*)&wbuf[q & 1][(2 * rg + 1) * KK + k4];
#pragma unroll
            for (int b = 0; b < 8; ++b) {
                float2 xv = *(const float2*)&xb[il][b][q * 4 + 2 * rg];
                dst[b].x = fmaf(xv.x, wA.x, dst[b].x);
                dst[b].y = fmaf(xv.x, wA.y, dst[b].y);
                dst[b].z = fmaf(xv.x, wA.z, dst[b].z);
                dst[b].w = fmaf(xv.x, wA.w, dst[b].w);
                dst[b].x = fmaf(xv.y, wB.x, dst[b].x);
                dst[b].y = fmaf(xv.y, wB.y, dst[b].y);
                dst[b].z = fmaf(xv.y, wB.z, dst[b].z);
                dst[b].w = fmaf(xv.y, wB.w, dst[b].w);
            }
        }
    };

    issue(0); issue(1);

#pragma unroll 1
    for (int il = 0; il < 8; ++il) {
        float4 v[8];
#pragma unroll
        for (int b = 0; b < 8; ++b) v[b] = make_float4(0.f, 0.f, 0.f, 0.f);

#pragma unroll
        for (int q = 0; q < 4; ++q) {
            if (q < 2) { if (il > 0) { WAITVM12; } else { WAITVM4; } }
            else if (q == 3) { if (il == 7) { WAITVM0; } else { WAITVM4; } }
            else { WAITVM4; }
            computequarter(il, q, v);
            WAITLGKM;
            if (il < 7 || q < 2) issue(il * 4 + q + 2);
        }

        const size_t vbase = ((size_t)(pairid + il * NGRP) * BS + half * 8) * (KK / 2) + 2 * t;
#pragma unroll
        for (int b = 0; b < 8; ++b) {
            acc[b].x += v[b].x; acc[b].y += v[b].y;
            acc[b].z += v[b].z; acc[b].w += v[b].w;
            uint2 pk;
            pk.x = pack2(v[b].x, v[b].y);
            pk.y = pack2(v[b].z, v[b].w);
            *(uint2*)&votes[vbase + (size_t)b * (KK / 2)] = pk;
        }
        MEMFENCE;
    }

    // epilogue is outside the ledger (last wait was il=7 q3's WAITVM0)
#pragma unroll
    for (int b = 0; b < 8; ++b) {
        uint2 pk;
        pk.x = pack2(acc[b].x, acc[b].y);
        pk.y = pack2(acc[b].z, acc[b].w);
        *(uint2*)&partials_bf[((size_t)pairid * BS + half * 8 + b) * (KK / 2) + 2 * t] = pk;
    }
}

// ---------------- routing from bf16 votes (r13/r15 structure) --------------
// Linearity: iter-3 logits = v.act1 + v.act2 = v.(act1+act2), so route2 is
// route1 with actb = act1+act2. Partials stored as packed bf16 (r18-proven).
#define RILBODY(IL, VC, VN)                                                    \
  {                                                                            \
    const int buf = (IL) & 1;                                                  \
    if ((IL) < 7) {                                                            \
      _Pragma("unroll")                                                        \
      for (int lb = 0; lb < 2; ++lb)                                           \
        VN[lb] = *(const uint4*)&votes[((size_t)(gid + ((IL) + 1) * NGRP) * BS \
                                        + bg0 + lb) * (KK / 2) + 4 * ks];      \
    }                                                                          \
    float dv[2];                                                               \
    _Pragma("unroll")                                                          \
    for (int lb = 0; lb < 2; ++lb) {                                           \
      float4 a0 = *(const float4*)&actb[2 * bh + lb][k8];                      \
      float4 a1 = *(const float4*)&actb[2 * bh + lb][k8 + 4];                  \
      float d = bflo(VC[lb].x) * a0.x + bfhi(VC[lb].x) * a0.y                  \
              + bflo(VC[lb].y) * a0.z + bfhi(VC[lb].y) * a0.w                  \
              + bflo(VC[lb].z) * a1.x + bfhi(VC[lb].z) * a1.y                  \
              + bflo(VC[lb].w) * a1.z + bfhi(VC[lb].w) * a1.w;                 \
      d += __shfl_xor(d, 1, 4);                                                \
      d += __shfl_xor(d, 2, 4);                                                \
      dv[lb] = d;                                                              \
    }                                                                          \
    if (j4 == 0) sm[buf][(2 * bh) * 65 + co] = dv[0];                          \
    if (j4 == 1) sm[buf][(2 * bh + 1) * 65 + co] = dv[1];                      \
    WAITLGKM; BAR();                                                           \
    if (t < 256) {                                                             \
      float l0 = sm[buf][(t >> 6) * 65 + (t & 63)];                            \
      float mx = l0;                                                           \
      mx = fmaxf(mx, __shfl_xor(mx, 1, 64));                                   \
      mx = fmaxf(mx, __shfl_xor(mx, 2, 64));                                   \
      mx = fmaxf(mx, __shfl_xor(mx, 4, 64));                                   \
      mx = fmaxf(mx, __shfl_xor(mx, 8, 64));                                   \
      mx = fmaxf(mx, __shfl_xor(mx, 16, 64));                                  \
      mx = fmaxf(mx, __shfl_xor(mx, 32, 64));                                  \
      float e = __expf(l0 - mx);                                               \
      float ssum = e;                                                          \
      ssum += __shfl_xor(ssum, 1, 64);                                         \
      ssum += __shfl_xor(ssum, 2, 64);                                         \
      ssum += __shfl_xor(ssum, 4, 64);                                         \
      ssum += __shfl_xor(ssum, 8, 64);                                         \
      ssum += __shfl_xor(ssum, 16, 64);                                        \
      ssum += __shfl_xor(ssum, 32, 64);                                        \
      sm[buf][(t >> 6) * 65 + (t & 63)] = e / ssum;                            \
      WAITLGKM;                                                                \
    }                                                                          \
    BAR();                                                                     \
    _Pragma("unroll")                                                          \
    for (int lb = 0; lb < 2; ++lb) {                                           \
      float r = sm[buf][(2 * bh + lb) * 65 + co];                              \
      acc[2 * lb + 0].x = fmaf(r, bflo(VC[lb].x), acc[2 * lb + 0].x);          \
      acc[2 * lb + 0].y = fmaf(r, bfhi(VC[lb].x), acc[2 * lb + 0].y);          \
      acc[2 * lb + 0].z = fmaf(r, bflo(VC[lb].y), acc[2 * lb + 0].z);          \
      acc[2 * lb + 0].w = fmaf(r, bfhi(VC[lb].y), acc[2 * lb + 0].w);          \
      acc[2 * lb + 1].x = fmaf(r, bflo(VC[lb].z), acc[2 * lb + 1].x);          \
      acc[2 * lb + 1].y = fmaf(r, bfhi(VC[lb].z), acc[2 * lb + 1].y);          \
      acc[2 * lb + 1].z = fmaf(r, bflo(VC[lb].w), acc[2 * lb + 1].z);          \
      acc[2 * lb + 1].w = fmaf(r, bfhi(VC[lb].w), acc[2 * lb + 1].w);          \
    }                                                                          \
  }

template <bool TWOACT>
__global__ __launch_bounds__(512, 2) void route_kernel(
    const unsigned* __restrict__ votes,   // [CI][BS][KK/2]
    const float* __restrict__ act1,       // [BS][KK]
    const float* __restrict__ act2,       // [BS][KK] (TWOACT only)
    unsigned* __restrict__ partials_bf)   // [NGRP][BS][KK/2] packed bf16
{
    __shared__ float actb[4][KK];   // 32 KB (act1 or act1+act2)
    __shared__ float sm[2][4 * 65]; // 2 KB, double-buffered per il

    const int t = threadIdx.x;       // 0..511
    const int phys = blockIdx.x;     // 0..1023
    const int xcd = phys & 7;
    const int slot = phys >> 3;      // 0..127
    const int gid = xcd * 32 + (slot >> 2);  // 0..255
    const int quarter = slot & 3;    // batches quarter*4 .. +3

    const int ks = t & 255;          // k-slice
    const int k8 = 8 * ks;
    const int co = ks >> 2;
    const int j4 = ks & 3;
    const int bh = t >> 8;           // 0/1: local batch pair
    const int bg0 = quarter * 4 + 2 * bh;

    {   // stage act (sum of two for TWOACT)
        int br = t >> 7, e0 = (t & 127) * 16;
#pragma unroll
        for (int r = 0; r < 4; ++r) {
            float4 u = *(const float4*)&act1[(size_t)(quarter * 4 + br) * KK + e0 + 4 * r];
            if constexpr (TWOACT) {
                float4 u2 = *(const float4*)&act2[(size_t)(quarter * 4 + br) * KK + e0 + 4 * r];
                u.x += u2.x; u.y += u2.y; u.z += u2.z; u.w += u2.w;
            }
            *(float4*)&actb[br][e0 + 4 * r] = u;
        }
    }
    __syncthreads();

    float4 acc[4];
#pragma unroll
    for (int i = 0; i < 4; ++i) acc[i] = make_float4(0.f, 0.f, 0.f, 0.f);

    uint4 vA[2], vB[2];
#pragma unroll
    for (int lb = 0; lb < 2; ++lb)
        vA[lb] = *(const uint4*)&votes[((size_t)gid * BS + bg0 + lb) * (KK / 2) + 4 * ks];

    RILBODY(0, vA, vB)
    RILBODY(1, vB, vA)
    RILBODY(2, vA, vB)
    RILBODY(3, vB, vA)
    RILBODY(4, vA, vB)
    RILBODY(5, vB, vA)
    RILBODY(6, vA, vB)
    RILBODY(7, vB, vA)

#pragma unroll
    for (int lb = 0; lb < 2; ++lb) {
        uint4 pk;
        pk.x = pack2(acc[2 * lb + 0].x, acc[2 * lb + 0].y);
        pk.y = pack2(acc[2 * lb + 0].z, acc[2 * lb + 0].w);
        pk.z = pack2(acc[2 * lb + 1].x, acc[2 * lb + 1].y);
        pk.w = pack2(acc[2 * lb + 1].z, acc[2 * lb + 1].w);
        *(uint4*)&partials_bf[((size_t)gid * BS + bg0 + lb) * (KK / 2) + 4 * ks] = pk;
    }
}

// bf16 reduce (all paths): 256 blocks x 128 thr, 4-way split + LDS combine
__global__ __launch_bounds__(128) void reduce_squash_bf(
    const unsigned* __restrict__ partials_bf,  // [NGRP][BS][KK/2]
    const float* __restrict__ bias,
    float* __restrict__ act_out, float scale)
{
    __shared__ float4 sred[4][32];
    const int t = threadIdx.x;
    const int blk = blockIdx.x;
    const int lane = t & 31;
    const int gp = t >> 5;
    const int o4 = blk * 128 + lane * 4;
    const int b = o4 >> 11;
    const int kk = o4 & (KK - 1);
    const unsigned* p = partials_bf + (size_t)b * (KK / 2) + kk / 2;
    const size_t stride = (size_t)BS * (KK / 2);

    float4 s = make_float4(0.f, 0.f, 0.f, 0.f);
#pragma unroll 4
    for (int g = gp * 64; g < gp * 64 + 64; ++g) {
        uint2 u = *(const uint2*)(p + (size_t)g * stride);
        s.x += bflo(u.x); s.y += bfhi(u.x);
        s.z += bflo(u.y); s.w += bfhi(u.y);
    }
    sred[gp][lane] = s;
    __syncthreads();

    if (t < 32) {
        float4 v0 = sred[0][t], v1 = sred[1][t], v2 = sred[2][t], v3 = sred[3][t];
        float4 v;
        v.x = (v0.x + v1.x) + (v2.x + v3.x);
        v.y = (v0.y + v1.y) + (v2.y + v3.y);
        v.z = (v0.z + v1.z) + (v2.z + v3.z);
        v.w = (v0.w + v1.w) + (v2.w + v3.w);
        const int ot = blk * 128 + t * 4;
        float4 bb = *(const float4*)&bias[ot & (KK - 1)];
        v.x = v.x * scale + bb.x;
        v.y = v.y * scale + bb.y;
        v.z = v.z * scale + bb.z;
        v.w = v.w * scale + bb.w;
        float n2 = v.x * v.x + v.y * v.y + v.z * v.z + v.w * v.w;
#pragma unroll
        for (int m = 1; m < 8; m <<= 1) n2 += __shfl_xor(n2, m, 8);
        float norm = sqrtf(n2);
        float sc = norm / (1.f + n2);
        float4 o = make_float4(v.x * sc, v.y * sc, v.z * sc, v.w * sc);
        *(float4*)&act_out[ot] = o;
    }
}

extern "C" void kernel_launch(void* const* d_in, const int* in_sizes, int n_in,
                              void* d_out, int out_size, void* d_ws, size_t ws_size,
                              hipStream_t stream) {
    const float* x = (const float*)d_in[0];
    const float* w = (const float*)d_in[1];
    const float* bias = (const float*)d_in[2];
    float* out = (float*)d_out;

    char* p = (char*)d_ws;
    unsigned* votes = (unsigned*)p;       p += (size_t)CI * BS * KK * 2;   // 134 MB (bf16)
    unsigned* partials_bf = (unsigned*)p; p += (size_t)NGRP * BS * KK * 2; // 16.8 MB (bf16)
    float* act1 = (float*)p;              p += (size_t)BS * KK * 4;
    float* act2 = (float*)p;

    votes_kernel<<<2 * NGRP, 512, 0, stream>>>(x, w, votes, partials_bf);
    reduce_squash_bf<<<256, 128, 0, stream>>>(partials_bf, bias, act1, 1.0f / (float)CO);
    route_kernel<false><<<4 * NGRP, 512, 0, stream>>>(votes, act1, nullptr, partials_bf);
    reduce_squash_bf<<<256, 128, 0, stream>>>(partials_bf, bias, act2, 1.0f);
    route_kernel<true><<<4 * NGRP, 512, 0, stream>>>(votes, act1, act2, partials_bf);
    reduce_squash_bf<<<256, 128, 0, stream>>>(partials_bf, bias, out, 1.0f);
}